// Round 6
// baseline (245.636 us; speedup 1.0000x reference)
//
#include <hip/hip_runtime.h>
#include <math.h>

#define S 16
#define C 8
#define NB 64   // batch
#define L 4096
#define K 64    // chunks per batch
#define LC 64   // steps per chunk

#define SLOT 324  // bf16 elems per matrix slot = 648 B (162 banks % 32 == 2 -> quad-distinct slot bases)
#define RS 20     // row stride in elems (40 B -> conflict-free row-major scatters)

typedef __attribute__((ext_vector_type(8))) short bf16x8;
typedef __attribute__((ext_vector_type(4))) short bf16x4;
typedef __attribute__((ext_vector_type(4))) float f32x4;
typedef unsigned long long ull;

// ws byte layout:
#define WS_INIT 0       // f32[16]
#define WS_ACC  64      // f32[16]
#define WS_CNT  128     // int[64] last-block counters (zeroed by prep)
#define WS_CLOG 512     // f32[4096] (16 KB)
#define WS_TTT  16896   // bf16 TTT[(p*16+n)][cc'=64] (32 KB), B-frag-ready
#define WS_CP   49664   // bf16 chunkP[4096][256]; even chunk row-major, odd [col][row]

__device__ __forceinline__ float hsig(float x) {
    return x / (1.0f + fabsf(x)) * 0.5f + 0.5f;
}
__device__ __forceinline__ unsigned short f2bf(float f) {
    unsigned int u = __float_as_uint(f);
    return (unsigned short)((u + 0x7fffu + ((u >> 16) & 1u)) >> 16);
}

__device__ __forceinline__ bf16x8 ldfrag(const unsigned short* base, int lane) {
    int col = lane & 15, quad = lane >> 4;
    bf16x8 f = {0, 0, 0, 0, 0, 0, 0, 0};
    if (quad < 2) {  // quads 2,3 are the K-pad (16 -> 32)
        const bf16x4* p = (const bf16x4*)(base + col * RS + quad * 8);
        bf16x4 lo = p[0], hi = p[1];
        f[0] = lo[0]; f[1] = lo[1]; f[2] = lo[2]; f[3] = lo[3];
        f[4] = hi[0]; f[5] = hi[1]; f[6] = hi[2]; f[7] = hi[3];
    }
    return f;
}

__device__ __forceinline__ f32x4 prod2(const unsigned short* slots, int sa, int sb, int lane) {
    bf16x8 a = ldfrag(slots + sa * SLOT, lane);
    bf16x8 b = ldfrag(slots + sb * SLOT, lane);
    f32x4 c = {0.f, 0.f, 0.f, 0.f};
    return __builtin_amdgcn_mfma_f32_16x16x32_bf16(a, b, c, 0, 0, 0);
}

// Load a frag pair straight from a packed global chunkP pair (even row-major,
// odd [col][row]): both give lane-contiguous 16 B at col*16 + quad*8.
__device__ __forceinline__ bf16x8 ldfrag_g(const unsigned short* base, int lane) {
    int col = lane & 15, quad = lane >> 4;
    bf16x8 f = {0, 0, 0, 0, 0, 0, 0, 0};
    if (quad < 2) f = *(const bf16x8*)(base + col * 16 + quad * 8);
    return f;
}

__device__ __forceinline__ void store16(unsigned short* slot, f32x4 d, int lane, bool odd) {
    int col = lane & 15, quad = lane >> 4;
    if (odd) {
        ull pk = (ull)f2bf(d[0]) | ((ull)f2bf(d[1]) << 16)
               | ((ull)f2bf(d[2]) << 32) | ((ull)f2bf(d[3]) << 48);
        *(ull*)(slot + col * RS + quad * 4) = pk;
    } else {
#pragma unroll
        for (int r = 0; r < 4; r++) slot[(quad * 4 + r) * RS + col] = f2bf(d[r]);
    }
}

// Single block: normalize T/init/acc, zero counters, and build TTT[cc'] = T_c*T_c'.
__global__ void __launch_bounds__(256) prep_kernel(const float* __restrict__ invh_init,
                                                   const float* __restrict__ invh_T,
                                                   const float* __restrict__ invh_acc,
                                                   unsigned char* __restrict__ wsb) {
    __shared__ float Tn[2048];  // Tn[(p*8+c)*16 + n]
    __shared__ float si[S];
    int t = threadIdx.x;  // 256
    if (t < S * C) {
        float v[S]; float s = 0.f;
#pragma unroll
        for (int n = 0; n < S; n++) { v[n] = hsig(invh_T[t * S + n]); s += v[n]; }
        float inv = 1.f / s;
#pragma unroll
        for (int n = 0; n < S; n++) Tn[t * S + n] = v[n] * inv;
    }
    if (t < S) si[t] = hsig(invh_init[t]);
    if (t < 64) ((int*)(wsb + WS_CNT))[t] = 0;
    __syncthreads();
    if (t < S) {
        float s = 0.f;
#pragma unroll
        for (int n = 0; n < S; n++) s += si[n];
        ((float*)(wsb + WS_INIT))[t] = si[t] / s;
        ((float*)(wsb + WS_ACC))[t] = logf(hsig(invh_acc[t]));
    }
    int p = t >> 4, n = t & 15;
    ull* dst = (ull*)((unsigned short*)(wsb + WS_TTT) + t * 64);
#pragma unroll
    for (int g = 0; g < 16; g++) {
        ull pk = 0;
#pragma unroll
        for (int q = 0; q < 4; q++) {
            int cc = 4 * g + q, c = cc >> 3, c2 = cc & 7;
            float a = 0.f;
#pragma unroll
            for (int k = 0; k < S; k++) a += Tn[(p * 8 + c) * 16 + k] * Tn[(k * 8 + c2) * 16 + n];
            pk |= (ull)f2bf(a) << (16 * q);
        }
        dst[g] = pk;
    }
}

__global__ void __launch_bounds__(256) chunk_kernel(const float* __restrict__ logx,
                                                    unsigned char* __restrict__ wsb,
                                                    float* __restrict__ out) {
    // 62 slots: 0..31 pair-products Q_i; 32..47 lv1; 48..55 lv2; 56..59 lv3; 60..61 lv4.
    __shared__ __align__(16) unsigned short slots[62 * SLOT];  // 40176 B
    float* xs = (float*)(slots + 32 * SLOT);  // overlay (dead before lv1 writes)
    __shared__ int isLast;

    int tid = threadIdx.x, lane = tid & 63, w = tid >> 6;
    int col = lane & 15, quad = lane >> 4;
    int chunk = blockIdx.x, b = blockIdx.y;

    // B-frags for the pair-product construct (wave w owns p-tiles 4w..4w+3).
    const unsigned short* TTT = (const unsigned short*)(wsb + WS_TTT);
    bf16x8 bfr[4][2];
#pragma unroll
    for (int jj = 0; jj < 4; jj++) {
        int t = 4 * w + jj;
#pragma unroll
        for (int kk = 0; kk < 2; kk++)
            bfr[jj][kk] = *(const bf16x8*)(TTT + (t * 16 + col) * 64 + kk * 32 + quad * 8);
    }

    // Stage logx tile (512 f32, coalesced).
    const float* xg = logx + ((size_t)b * L + (size_t)chunk * LC) * C;
    xs[tid] = xg[tid];
    xs[tid + 256] = xg[tid + 256];
    __syncthreads();

    // Per-step logsumexp normalize (wave 0); chunkLog written here.
    if (tid < LC) {
        float v[C]; float m = -INFINITY;
#pragma unroll
        for (int c = 0; c < C; c++) { v[c] = xs[tid * C + c]; m = fmaxf(m, v[c]); }
        float s = 0.f;
#pragma unroll
        for (int c = 0; c < C; c++) { v[c] = __expf(v[c] - m); s += v[c]; }
        float lx = m + __logf(s);
        float inv = 1.0f / s;
#pragma unroll
        for (int c = 0; c < C; c++) xs[tid * C + c] = v[c] * inv;
        float cl = lx;
#pragma unroll
        for (int d = 1; d < 64; d <<= 1) cl += __shfl_xor(cl, d);
        if (lane == 0) ((float*)(wsb + WS_CLOG))[b * K + chunk] = cl;
    }
    __syncthreads();

    // A-frags: y[i][cc'] = xn[2i][c]*xn[2i+1][c'].
    bf16x8 afr[2][2];
#pragma unroll
    for (int mt = 0; mt < 2; mt++) {
        int i2 = 2 * (mt * 16 + col);
        const float4* x1p = (const float4*)(xs + (i2 + 1) * 8);
        float4 xa = x1p[0], xb = x1p[1];
#pragma unroll
        for (int kk = 0; kk < 2; kk++) {
            float x0 = xs[i2 * 8 + kk * 4 + quad];
            bf16x8 a;
            a[0] = (short)f2bf(x0 * xa.x); a[1] = (short)f2bf(x0 * xa.y);
            a[2] = (short)f2bf(x0 * xa.z); a[3] = (short)f2bf(x0 * xa.w);
            a[4] = (short)f2bf(x0 * xb.x); a[5] = (short)f2bf(x0 * xb.y);
            a[6] = (short)f2bf(x0 * xb.z); a[7] = (short)f2bf(x0 * xb.w);
            afr[mt][kk] = a;
        }
    }

    // Pair-product construct -> slots 0..31 (parity i&1).
#pragma unroll
    for (int mt = 0; mt < 2; mt++)
#pragma unroll
        for (int jj = 0; jj < 4; jj++) {
            f32x4 acc = {0.f, 0.f, 0.f, 0.f};
#pragma unroll
            for (int kk = 0; kk < 2; kk++)
                acc = __builtin_amdgcn_mfma_f32_16x16x32_bf16(afr[mt][kk], bfr[jj][kk], acc, 0, 0, 0);
            int t = 4 * w + jj;  // = p
#pragma unroll
            for (int r = 0; r < 4; r++) {
                int i = mt * 16 + quad * 4 + r;
                int off = (i & 1) ? (col * RS + t) : (t * RS + col);
                slots[i * SLOT + off] = f2bf(acc[r]);
            }
        }
    __syncthreads();

    // Tree over 32 (lv1..lv3 barrier-free via wave ownership).
#pragma unroll
    for (int i2 = 0; i2 < 4; i2++) {
        int i = 4 * w + i2;
        store16(slots + (32 + i) * SLOT, prod2(slots, 2 * i, 2 * i + 1, lane), lane, i & 1);
    }
#pragma unroll
    for (int i2 = 0; i2 < 2; i2++) {
        int i = 2 * w + i2;
        store16(slots + (48 + i) * SLOT, prod2(slots, 32 + 2 * i, 32 + 2 * i + 1, lane), lane, i & 1);
    }
    store16(slots + (56 + w) * SLOT, prod2(slots, 48 + 2 * w, 48 + 2 * w + 1, lane), lane, w & 1);
    __syncthreads();
    if (w < 2)
        store16(slots + (60 + w) * SLOT, prod2(slots, 56 + 2 * w, 56 + 2 * w + 1, lane), lane, w & 1);
    __syncthreads();
    f32x4 root = prod2(slots, 60, 61, lane);

    unsigned short* cpb = (unsigned short*)(wsb + WS_CP) + (size_t)b * K * 256;
    if (w == 0) {
        unsigned short* cp = cpb + (size_t)chunk * 256;
        if (chunk & 1) {
            ull pk = (ull)f2bf(root[0]) | ((ull)f2bf(root[1]) << 16)
                   | ((ull)f2bf(root[2]) << 32) | ((ull)f2bf(root[3]) << 48);
            *(ull*)(cp + col * 16 + quad * 4) = pk;
        } else {
#pragma unroll
            for (int r = 0; r < 4; r++) cp[(quad * 4 + r) * 16 + col] = f2bf(root[r]);
        }
    }
    __syncthreads();  // all tree reads done; slots reusable; w0 store issued

    if (tid == 0) {
        __threadfence();  // release: drain + write back past per-XCD L2
        int prev = atomicAdd((int*)(wsb + WS_CNT) + b, 1);
        isLast = (prev == K - 1) ? 1 : 0;
    }
    __syncthreads();
    if (!isLast) return;
    __threadfence();  // acquire: invalidate stale cache lines

    // ---- last block for batch b: fold the 64 chunk products ----
    // lv1 from global (wave w owns i = 8w..8w+7 -> slots 8w..8w+7).
#pragma unroll
    for (int i2 = 0; i2 < 8; i2++) {
        int i = 8 * w + i2;
        bf16x8 a = ldfrag_g(cpb + (size_t)(2 * i) * 256, lane);
        bf16x8 bb = ldfrag_g(cpb + (size_t)(2 * i + 1) * 256, lane);
        f32x4 c0 = {0.f, 0.f, 0.f, 0.f};
        f32x4 d = __builtin_amdgcn_mfma_f32_16x16x32_bf16(a, bb, c0, 0, 0, 0);
        store16(slots + i * SLOT, d, lane, i & 1);
    }
    // identical tail tree over 32
#pragma unroll
    for (int i2 = 0; i2 < 4; i2++) {
        int i = 4 * w + i2;
        store16(slots + (32 + i) * SLOT, prod2(slots, 2 * i, 2 * i + 1, lane), lane, i & 1);
    }
#pragma unroll
    for (int i2 = 0; i2 < 2; i2++) {
        int i = 2 * w + i2;
        store16(slots + (48 + i) * SLOT, prod2(slots, 32 + 2 * i, 32 + 2 * i + 1, lane), lane, i & 1);
    }
    store16(slots + (56 + w) * SLOT, prod2(slots, 48 + 2 * w, 48 + 2 * w + 1, lane), lane, w & 1);
    __syncthreads();
    if (w < 2)
        store16(slots + (60 + w) * SLOT, prod2(slots, 56 + 2 * w, 56 + 2 * w + 1, lane), lane, w & 1);
    __syncthreads();
    f32x4 troot = prod2(slots, 60, 61, lane);

    if (w == 0) {
        const float* initp = (const float*)(wsb + WS_INIT);
        const float* acclog = (const float*)(wsb + WS_ACC);
        float part = 0.f;
#pragma unroll
        for (int r = 0; r < 4; r++) part += initp[quad * 4 + r] * troot[r];
        part += __shfl_xor(part, 16);
        part += __shfl_xor(part, 32);
        float lp = logf(fmaxf(part, 0.f) + 1e-30f) + acclog[col];
        float mx = lp;
#pragma unroll
        for (int d = 1; d < 16; d <<= 1) mx = fmaxf(mx, __shfl_xor(mx, d));
        float a2 = isfinite(mx) ? mx : 0.0f;  // jax.nn.logsumexp semantics
        float sm = expf(lp - a2);
#pragma unroll
        for (int d = 1; d < 16; d <<= 1) sm += __shfl_xor(sm, d);
        float cl = ((const float*)(wsb + WS_CLOG))[b * K + lane];
#pragma unroll
        for (int d = 1; d < 64; d <<= 1) cl += __shfl_xor(cl, d);
        if (lane == 0) out[b] = logf(sm) + a2 + cl;
    }
}

extern "C" void kernel_launch(void* const* d_in, const int* in_sizes, int n_in,
                              void* d_out, int out_size, void* d_ws, size_t ws_size,
                              hipStream_t stream) {
    const float* logx = (const float*)d_in[0];   // (B, L, C) f32
    const float* init = (const float*)d_in[1];   // (S,) f32
    const float* T    = (const float*)d_in[2];   // (S, C, S) f32
    const float* acc  = (const float*)d_in[3];   // (S,) f32
    unsigned char* wsb = (unsigned char*)d_ws;
    float* out = (float*)d_out;

    prep_kernel<<<1, 256, 0, stream>>>(init, T, acc, wsb);
    chunk_kernel<<<dim3(K, NB), 256, 0, stream>>>(logx, wsb, out);
}

// Round 7
// 115.211 us; speedup vs baseline: 2.1320x; 2.1320x over previous
//
#include <hip/hip_runtime.h>
#include <math.h>

#define S 16
#define C 8
#define NB 64   // batch
#define L 4096
#define K 64    // chunks per batch
#define LC 64   // steps per chunk

#define SLOT 324  // bf16 elems per matrix slot = 648 B (162 banks % 32 == 2 -> quad-distinct slot bases)
#define RS 20     // row stride in elems (40 B -> conflict-free row-major scatters)

typedef __attribute__((ext_vector_type(8))) short bf16x8;
typedef __attribute__((ext_vector_type(4))) short bf16x4;
typedef __attribute__((ext_vector_type(4))) float f32x4;
typedef unsigned long long ull;

// ws byte layout:
#define WS_INIT 0       // f32[16]
#define WS_ACC  64      // f32[16]
#define WS_CLOG 512     // f32[4096] (16 KB)
#define WS_TTT  16896   // bf16 TTT[(p*16+n)][cc'=64] (32 KB), B-frag-ready
#define WS_CP   49664   // bf16 chunkP[4096][256]; even chunk row-major, odd [col][row]

__device__ __forceinline__ float hsig(float x) {
    return x / (1.0f + fabsf(x)) * 0.5f + 0.5f;
}
__device__ __forceinline__ unsigned short f2bf(float f) {
    unsigned int u = __float_as_uint(f);
    return (unsigned short)((u + 0x7fffu + ((u >> 16) & 1u)) >> 16);
}

__device__ __forceinline__ bf16x8 ldfrag(const unsigned short* base, int lane) {
    int col = lane & 15, quad = lane >> 4;
    bf16x8 f = {0, 0, 0, 0, 0, 0, 0, 0};
    if (quad < 2) {  // quads 2,3 are the K-pad (16 -> 32)
        const bf16x4* p = (const bf16x4*)(base + col * RS + quad * 8);
        bf16x4 lo = p[0], hi = p[1];
        f[0] = lo[0]; f[1] = lo[1]; f[2] = lo[2]; f[3] = lo[3];
        f[4] = hi[0]; f[5] = hi[1]; f[6] = hi[2]; f[7] = hi[3];
    }
    return f;
}

__device__ __forceinline__ f32x4 prod2(const unsigned short* slots, int sa, int sb, int lane) {
    bf16x8 a = ldfrag(slots + sa * SLOT, lane);
    bf16x8 b = ldfrag(slots + sb * SLOT, lane);
    f32x4 c = {0.f, 0.f, 0.f, 0.f};
    return __builtin_amdgcn_mfma_f32_16x16x32_bf16(a, b, c, 0, 0, 0);
}

// Frag straight from a packed global chunkP matrix (even chunk row-major ->
// A-operand; odd chunk [col][row] -> B-operand): 16 B/lane at col*16+quad*8.
__device__ __forceinline__ bf16x8 ldfrag_g(const unsigned short* base, int lane) {
    int col = lane & 15, quad = lane >> 4;
    bf16x8 f = {0, 0, 0, 0, 0, 0, 0, 0};
    if (quad < 2) f = *(const bf16x8*)(base + col * 16 + quad * 8);
    return f;
}

__device__ __forceinline__ void store16(unsigned short* slot, f32x4 d, int lane, bool odd) {
    int col = lane & 15, quad = lane >> 4;
    if (odd) {
        ull pk = (ull)f2bf(d[0]) | ((ull)f2bf(d[1]) << 16)
               | ((ull)f2bf(d[2]) << 32) | ((ull)f2bf(d[3]) << 48);
        *(ull*)(slot + col * RS + quad * 4) = pk;
    } else {
#pragma unroll
        for (int r = 0; r < 4; r++) slot[(quad * 4 + r) * RS + col] = f2bf(d[r]);
    }
}

// Single block: normalize T/init/acc and build TTT[cc'] = T_c * T_{c'} (B-frag-ready).
__global__ void __launch_bounds__(256) prep_kernel(const float* __restrict__ invh_init,
                                                   const float* __restrict__ invh_T,
                                                   const float* __restrict__ invh_acc,
                                                   unsigned char* __restrict__ wsb) {
    __shared__ float Tn[2048];  // Tn[(p*8+c)*16 + n]
    __shared__ float si[S];
    int t = threadIdx.x;  // 256
    if (t < S * C) {
        float v[S]; float s = 0.f;
#pragma unroll
        for (int n = 0; n < S; n++) { v[n] = hsig(invh_T[t * S + n]); s += v[n]; }
        float inv = 1.f / s;
#pragma unroll
        for (int n = 0; n < S; n++) Tn[t * S + n] = v[n] * inv;
    }
    if (t < S) si[t] = hsig(invh_init[t]);
    __syncthreads();
    if (t < S) {
        float s = 0.f;
#pragma unroll
        for (int n = 0; n < S; n++) s += si[n];
        ((float*)(wsb + WS_INIT))[t] = si[t] / s;
        ((float*)(wsb + WS_ACC))[t] = logf(hsig(invh_acc[t]));
    }
    int p = t >> 4, n = t & 15;
    ull* dst = (ull*)((unsigned short*)(wsb + WS_TTT) + t * 64);
#pragma unroll
    for (int g = 0; g < 16; g++) {
        ull pk = 0;
#pragma unroll
        for (int q = 0; q < 4; q++) {
            int cc = 4 * g + q, c = cc >> 3, c2 = cc & 7;
            float a = 0.f;
#pragma unroll
            for (int k = 0; k < S; k++) a += Tn[(p * 8 + c) * 16 + k] * Tn[(k * 8 + c2) * 16 + n];
            pk |= (ull)f2bf(a) << (16 * q);
        }
        dst[g] = pk;
    }
}

__global__ void __launch_bounds__(256) chunk_kernel(const float* __restrict__ logx,
                                                    unsigned char* __restrict__ wsb) {
    // 62 slots: 0..31 pair-products Q_i; 32..47 lv1; 48..55 lv2; 56..59 lv3; 60..61 lv4.
    __shared__ __align__(16) unsigned short slots[62 * SLOT];  // 40176 B
    float* xs = (float*)(slots + 32 * SLOT);  // overlay (dead before lv1 writes)

    int tid = threadIdx.x, lane = tid & 63, w = tid >> 6;
    int col = lane & 15, quad = lane >> 4;
    int chunk = blockIdx.x, b = blockIdx.y;

    // B-frags for the pair-product construct (wave w owns p-tiles 4w..4w+3).
    const unsigned short* TTT = (const unsigned short*)(wsb + WS_TTT);
    bf16x8 bfr[4][2];
#pragma unroll
    for (int jj = 0; jj < 4; jj++) {
        int t = 4 * w + jj;
#pragma unroll
        for (int kk = 0; kk < 2; kk++)
            bfr[jj][kk] = *(const bf16x8*)(TTT + (t * 16 + col) * 64 + kk * 32 + quad * 8);
    }

    // Stage logx tile (512 f32, coalesced).
    const float* xg = logx + ((size_t)b * L + (size_t)chunk * LC) * C;
    xs[tid] = xg[tid];
    xs[tid + 256] = xg[tid + 256];
    __syncthreads();

    // Per-step logsumexp normalize (wave 0); chunkLog written here.
    if (tid < LC) {
        float v[C]; float m = -INFINITY;
#pragma unroll
        for (int c = 0; c < C; c++) { v[c] = xs[tid * C + c]; m = fmaxf(m, v[c]); }
        float s = 0.f;
#pragma unroll
        for (int c = 0; c < C; c++) { v[c] = __expf(v[c] - m); s += v[c]; }
        float lx = m + __logf(s);
        float inv = 1.0f / s;
#pragma unroll
        for (int c = 0; c < C; c++) xs[tid * C + c] = v[c] * inv;
        float cl = lx;
#pragma unroll
        for (int d = 1; d < 64; d <<= 1) cl += __shfl_xor(cl, d);
        if (lane == 0) ((float*)(wsb + WS_CLOG))[b * K + chunk] = cl;
    }
    __syncthreads();

    // A-frags: y[i][cc'] = xn[2i][c]*xn[2i+1][c'].
    bf16x8 afr[2][2];
#pragma unroll
    for (int mt = 0; mt < 2; mt++) {
        int i2 = 2 * (mt * 16 + col);
        const float4* x1p = (const float4*)(xs + (i2 + 1) * 8);
        float4 xa = x1p[0], xb = x1p[1];
#pragma unroll
        for (int kk = 0; kk < 2; kk++) {
            float x0 = xs[i2 * 8 + kk * 4 + quad];
            bf16x8 a;
            a[0] = (short)f2bf(x0 * xa.x); a[1] = (short)f2bf(x0 * xa.y);
            a[2] = (short)f2bf(x0 * xa.z); a[3] = (short)f2bf(x0 * xa.w);
            a[4] = (short)f2bf(x0 * xb.x); a[5] = (short)f2bf(x0 * xb.y);
            a[6] = (short)f2bf(x0 * xb.z); a[7] = (short)f2bf(x0 * xb.w);
            afr[mt][kk] = a;
        }
    }

    // Pair-product construct -> slots 0..31 (parity i&1).
#pragma unroll
    for (int mt = 0; mt < 2; mt++)
#pragma unroll
        for (int jj = 0; jj < 4; jj++) {
            f32x4 acc = {0.f, 0.f, 0.f, 0.f};
#pragma unroll
            for (int kk = 0; kk < 2; kk++)
                acc = __builtin_amdgcn_mfma_f32_16x16x32_bf16(afr[mt][kk], bfr[jj][kk], acc, 0, 0, 0);
            int t = 4 * w + jj;  // = p
#pragma unroll
            for (int r = 0; r < 4; r++) {
                int i = mt * 16 + quad * 4 + r;
                int off = (i & 1) ? (col * RS + t) : (t * RS + col);
                slots[i * SLOT + off] = f2bf(acc[r]);
            }
        }
    __syncthreads();

    // Tree over 32 (lv1..lv3 barrier-free via wave ownership).
#pragma unroll
    for (int i2 = 0; i2 < 4; i2++) {
        int i = 4 * w + i2;
        store16(slots + (32 + i) * SLOT, prod2(slots, 2 * i, 2 * i + 1, lane), lane, i & 1);
    }
#pragma unroll
    for (int i2 = 0; i2 < 2; i2++) {
        int i = 2 * w + i2;
        store16(slots + (48 + i) * SLOT, prod2(slots, 32 + 2 * i, 32 + 2 * i + 1, lane), lane, i & 1);
    }
    store16(slots + (56 + w) * SLOT, prod2(slots, 48 + 2 * w, 48 + 2 * w + 1, lane), lane, w & 1);
    __syncthreads();
    if (w < 2)
        store16(slots + (60 + w) * SLOT, prod2(slots, 56 + 2 * w, 56 + 2 * w + 1, lane), lane, w & 1);
    __syncthreads();
    f32x4 root = prod2(slots, 60, 61, lane);

    if (w == 0) {
        unsigned short* cp = (unsigned short*)(wsb + WS_CP) + ((size_t)b * K + chunk) * 256;
        if (chunk & 1) {
            ull pk = (ull)f2bf(root[0]) | ((ull)f2bf(root[1]) << 16)
                   | ((ull)f2bf(root[2]) << 32) | ((ull)f2bf(root[3]) << 48);
            *(ull*)(cp + col * 16 + quad * 4) = pk;
        } else {
#pragma unroll
            for (int r = 0; r < 4; r++) cp[(quad * 4 + r) * 16 + col] = f2bf(root[r]);
        }
    }
}

__global__ void __launch_bounds__(256) reduce_kernel(unsigned char* __restrict__ wsb,
                                                     float* __restrict__ out) {
    // Same 62-slot layout as chunk: lv1 (from global) -> 0..31, then tree over 32.
    __shared__ __align__(16) unsigned short slots[62 * SLOT];
    int tid = threadIdx.x, lane = tid & 63, w = tid >> 6;
    int col = lane & 15, quad = lane >> 4;
    int b = blockIdx.x;

    const unsigned short* cpb = (const unsigned short*)(wsb + WS_CP) + (size_t)b * K * 256;
    // lv1: 32 products of global pairs (even = A row-major, odd = B [col][row]).
#pragma unroll
    for (int i2 = 0; i2 < 8; i2++) {
        int i = 8 * w + i2;
        bf16x8 a  = ldfrag_g(cpb + (size_t)(2 * i) * 256, lane);
        bf16x8 bb = ldfrag_g(cpb + (size_t)(2 * i + 1) * 256, lane);
        f32x4 c0 = {0.f, 0.f, 0.f, 0.f};
        f32x4 d = __builtin_amdgcn_mfma_f32_16x16x32_bf16(a, bb, c0, 0, 0, 0);
        store16(slots + i * SLOT, d, lane, i & 1);
    }
#pragma unroll
    for (int i2 = 0; i2 < 4; i2++) {
        int i = 4 * w + i2;
        store16(slots + (32 + i) * SLOT, prod2(slots, 2 * i, 2 * i + 1, lane), lane, i & 1);
    }
#pragma unroll
    for (int i2 = 0; i2 < 2; i2++) {
        int i = 2 * w + i2;
        store16(slots + (48 + i) * SLOT, prod2(slots, 32 + 2 * i, 32 + 2 * i + 1, lane), lane, i & 1);
    }
    store16(slots + (56 + w) * SLOT, prod2(slots, 48 + 2 * w, 48 + 2 * w + 1, lane), lane, w & 1);
    __syncthreads();
    if (w < 2)
        store16(slots + (60 + w) * SLOT, prod2(slots, 56 + 2 * w, 56 + 2 * w + 1, lane), lane, w & 1);
    __syncthreads();
    f32x4 troot = prod2(slots, 60, 61, lane);

    if (w == 0) {
        const float* initp = (const float*)(wsb + WS_INIT);
        const float* acclog = (const float*)(wsb + WS_ACC);
        float part = 0.f;
#pragma unroll
        for (int r = 0; r < 4; r++) part += initp[quad * 4 + r] * troot[r];
        part += __shfl_xor(part, 16);
        part += __shfl_xor(part, 32);
        float lp = logf(fmaxf(part, 0.f) + 1e-30f) + acclog[col];
        float mx = lp;
#pragma unroll
        for (int d = 1; d < 16; d <<= 1) mx = fmaxf(mx, __shfl_xor(mx, d));
        float a2 = isfinite(mx) ? mx : 0.0f;  // jax.nn.logsumexp semantics
        float sm = expf(lp - a2);
#pragma unroll
        for (int d = 1; d < 16; d <<= 1) sm += __shfl_xor(sm, d);
        float cl = ((const float*)(wsb + WS_CLOG))[b * K + lane];
#pragma unroll
        for (int d = 1; d < 64; d <<= 1) cl += __shfl_xor(cl, d);
        if (lane == 0) out[b] = logf(sm) + a2 + cl;
    }
}

extern "C" void kernel_launch(void* const* d_in, const int* in_sizes, int n_in,
                              void* d_out, int out_size, void* d_ws, size_t ws_size,
                              hipStream_t stream) {
    const float* logx = (const float*)d_in[0];   // (B, L, C) f32
    const float* init = (const float*)d_in[1];   // (S,) f32
    const float* T    = (const float*)d_in[2];   // (S, C, S) f32
    const float* acc  = (const float*)d_in[3];   // (S,) f32
    unsigned char* wsb = (unsigned char*)d_ws;
    float* out = (float*)d_out;

    prep_kernel<<<1, 256, 0, stream>>>(init, T, acc, wsb);
    chunk_kernel<<<dim3(K, NB), 256, 0, stream>>>(logx, wsb);
    reduce_kernel<<<NB, 256, 0, stream>>>(wsb, out);
}

// Round 8
// 93.767 us; speedup vs baseline: 2.6196x; 1.2287x over previous
//
#include <hip/hip_runtime.h>
#include <math.h>

#define S 16
#define C 8
#define NB 64   // batch
#define L 4096
#define K 64    // chunks per batch
#define LC 64   // steps per chunk

#define SLOT 324  // bf16 elems per matrix slot = 648 B (162 banks % 32 == 2 -> quad-distinct slot bases)
#define RS 20     // row stride in elems (40 B -> conflict-free row-major scatters)

typedef __attribute__((ext_vector_type(8))) short bf16x8;
typedef __attribute__((ext_vector_type(4))) short bf16x4;
typedef __attribute__((ext_vector_type(4))) float f32x4;
typedef unsigned long long ull;

// ws byte layout:
#define WS_INIT 0       // f32[16]
#define WS_ACC  64      // f32[16]
#define WS_CLOG 512     // f32[4096] (16 KB)
#define WS_TTT  16896   // bf16 TTT[(p*16+n)][cc'=64] (32 KB), B-frag-ready
#define WS_CP   49664   // bf16 chunkP[4096][256]; even chunk row-major, odd [col][row]

__device__ __forceinline__ float hsig(float x) {
    return x / (1.0f + fabsf(x)) * 0.5f + 0.5f;
}
__device__ __forceinline__ unsigned short f2bf(float f) {
    unsigned int u = __float_as_uint(f);
    return (unsigned short)((u + 0x7fffu + ((u >> 16) & 1u)) >> 16);
}

__device__ __forceinline__ bf16x8 ldfrag(const unsigned short* base, int lane) {
    int col = lane & 15, quad = lane >> 4;
    bf16x8 f = {0, 0, 0, 0, 0, 0, 0, 0};
    if (quad < 2) {  // quads 2,3 are the K-pad (16 -> 32)
        const bf16x4* p = (const bf16x4*)(base + col * RS + quad * 8);
        bf16x4 lo = p[0], hi = p[1];
        f[0] = lo[0]; f[1] = lo[1]; f[2] = lo[2]; f[3] = lo[3];
        f[4] = hi[0]; f[5] = hi[1]; f[6] = hi[2]; f[7] = hi[3];
    }
    return f;
}

__device__ __forceinline__ f32x4 prod2(const unsigned short* slots, int sa, int sb, int lane) {
    bf16x8 a = ldfrag(slots + sa * SLOT, lane);
    bf16x8 b = ldfrag(slots + sb * SLOT, lane);
    f32x4 c = {0.f, 0.f, 0.f, 0.f};
    return __builtin_amdgcn_mfma_f32_16x16x32_bf16(a, b, c, 0, 0, 0);
}

// Frag straight from a packed global chunkP matrix (even chunk row-major ->
// A-operand; odd chunk [col][row] -> B-operand): 16 B/lane at col*16+quad*8.
__device__ __forceinline__ bf16x8 ldfrag_g(const unsigned short* base, int lane) {
    int col = lane & 15, quad = lane >> 4;
    bf16x8 f = {0, 0, 0, 0, 0, 0, 0, 0};
    if (quad < 2) f = *(const bf16x8*)(base + col * 16 + quad * 8);
    return f;
}

__device__ __forceinline__ void store16(unsigned short* slot, f32x4 d, int lane, bool odd) {
    int col = lane & 15, quad = lane >> 4;
    if (odd) {
        ull pk = (ull)f2bf(d[0]) | ((ull)f2bf(d[1]) << 16)
               | ((ull)f2bf(d[2]) << 32) | ((ull)f2bf(d[3]) << 48);
        *(ull*)(slot + col * RS + quad * 4) = pk;
    } else {
#pragma unroll
        for (int r = 0; r < 4; r++) slot[(quad * 4 + r) * RS + col] = f2bf(d[r]);
    }
}

// 64 blocks: every block redundantly normalizes T in LDS (cheap), then block cc
// computes TTT[.][cc] = (T_c * T_{c'}) column. Block 0 also writes init/acc.
__global__ void __launch_bounds__(256) prepall_kernel(const float* __restrict__ invh_init,
                                                      const float* __restrict__ invh_T,
                                                      const float* __restrict__ invh_acc,
                                                      unsigned char* __restrict__ wsb) {
    __shared__ float Tn[2048];  // Tn[(p*8+c)*16 + n]
    int t = threadIdx.x;  // 256
    int cc = blockIdx.x, c = cc >> 3, c2 = cc & 7;
    if (t < S * C) {
        float v[S]; float s = 0.f;
#pragma unroll
        for (int n = 0; n < S; n++) { v[n] = hsig(invh_T[t * S + n]); s += v[n]; }
        float inv = 1.f / s;
#pragma unroll
        for (int n = 0; n < S; n++) Tn[t * S + n] = v[n] * inv;
    }
    __syncthreads();
    int p = t >> 4, n = t & 15;
    float a = 0.f;
#pragma unroll
    for (int k = 0; k < S; k++) a += Tn[(p * 8 + c) * 16 + k] * Tn[(k * 8 + c2) * 16 + n];
    ((unsigned short*)(wsb + WS_TTT))[t * 64 + cc] = f2bf(a);

    if (cc == 0 && t < S) {
        float s = 0.f;
#pragma unroll
        for (int k = 0; k < S; k++) s += hsig(invh_init[k]);
        ((float*)(wsb + WS_INIT))[t] = hsig(invh_init[t]) / s;
        ((float*)(wsb + WS_ACC))[t] = logf(hsig(invh_acc[t]));
    }
}

__global__ void __launch_bounds__(256) chunk_kernel(const float* __restrict__ logx,
                                                    unsigned char* __restrict__ wsb) {
    // 62 slots: 0..31 pair-products Q_i; 32..47 lv1; 48..55 lv2; 56..59 lv3; 60..61 lv4.
    __shared__ __align__(16) unsigned short slots[62 * SLOT];  // 40176 B
    float* xs = (float*)(slots + 32 * SLOT);  // overlay (dead before lv1 writes)

    int tid = threadIdx.x, lane = tid & 63, w = tid >> 6;
    int col = lane & 15, quad = lane >> 4;
    int chunk = blockIdx.x, b = blockIdx.y;

    // B-frags for the pair-product construct (wave w owns p-tiles 4w..4w+3).
    const unsigned short* TTT = (const unsigned short*)(wsb + WS_TTT);
    bf16x8 bfr[4][2];
#pragma unroll
    for (int jj = 0; jj < 4; jj++) {
        int t = 4 * w + jj;
#pragma unroll
        for (int kk = 0; kk < 2; kk++)
            bfr[jj][kk] = *(const bf16x8*)(TTT + (t * 16 + col) * 64 + kk * 32 + quad * 8);
    }

    // Stage logx tile (512 f32, coalesced).
    const float* xg = logx + ((size_t)b * L + (size_t)chunk * LC) * C;
    xs[tid] = xg[tid];
    xs[tid + 256] = xg[tid + 256];
    __syncthreads();

    // Per-step logsumexp normalize (wave 0); chunkLog written here.
    if (tid < LC) {
        float v[C]; float m = -INFINITY;
#pragma unroll
        for (int c = 0; c < C; c++) { v[c] = xs[tid * C + c]; m = fmaxf(m, v[c]); }
        float s = 0.f;
#pragma unroll
        for (int c = 0; c < C; c++) { v[c] = __expf(v[c] - m); s += v[c]; }
        float lx = m + __logf(s);
        float inv = 1.0f / s;
#pragma unroll
        for (int c = 0; c < C; c++) xs[tid * C + c] = v[c] * inv;
        float cl = lx;
#pragma unroll
        for (int d = 1; d < 64; d <<= 1) cl += __shfl_xor(cl, d);
        if (lane == 0) ((float*)(wsb + WS_CLOG))[b * K + chunk] = cl;
    }
    __syncthreads();

    // A-frags: y[i][cc'] = xn[2i][c]*xn[2i+1][c'].
    bf16x8 afr[2][2];
#pragma unroll
    for (int mt = 0; mt < 2; mt++) {
        int i2 = 2 * (mt * 16 + col);
        const float4* x1p = (const float4*)(xs + (i2 + 1) * 8);
        float4 xa = x1p[0], xb = x1p[1];
#pragma unroll
        for (int kk = 0; kk < 2; kk++) {
            float x0 = xs[i2 * 8 + kk * 4 + quad];
            bf16x8 a;
            a[0] = (short)f2bf(x0 * xa.x); a[1] = (short)f2bf(x0 * xa.y);
            a[2] = (short)f2bf(x0 * xa.z); a[3] = (short)f2bf(x0 * xa.w);
            a[4] = (short)f2bf(x0 * xb.x); a[5] = (short)f2bf(x0 * xb.y);
            a[6] = (short)f2bf(x0 * xb.z); a[7] = (short)f2bf(x0 * xb.w);
            afr[mt][kk] = a;
        }
    }

    // Pair-product construct -> slots 0..31 (parity i&1).
#pragma unroll
    for (int mt = 0; mt < 2; mt++)
#pragma unroll
        for (int jj = 0; jj < 4; jj++) {
            f32x4 acc = {0.f, 0.f, 0.f, 0.f};
#pragma unroll
            for (int kk = 0; kk < 2; kk++)
                acc = __builtin_amdgcn_mfma_f32_16x16x32_bf16(afr[mt][kk], bfr[jj][kk], acc, 0, 0, 0);
            int t = 4 * w + jj;  // = p
#pragma unroll
            for (int r = 0; r < 4; r++) {
                int i = mt * 16 + quad * 4 + r;
                int off = (i & 1) ? (col * RS + t) : (t * RS + col);
                slots[i * SLOT + off] = f2bf(acc[r]);
            }
        }
    __syncthreads();

    // Tree over 32 (lv1..lv3 barrier-free via wave ownership).
#pragma unroll
    for (int i2 = 0; i2 < 4; i2++) {
        int i = 4 * w + i2;
        store16(slots + (32 + i) * SLOT, prod2(slots, 2 * i, 2 * i + 1, lane), lane, i & 1);
    }
#pragma unroll
    for (int i2 = 0; i2 < 2; i2++) {
        int i = 2 * w + i2;
        store16(slots + (48 + i) * SLOT, prod2(slots, 32 + 2 * i, 32 + 2 * i + 1, lane), lane, i & 1);
    }
    store16(slots + (56 + w) * SLOT, prod2(slots, 48 + 2 * w, 48 + 2 * w + 1, lane), lane, w & 1);
    __syncthreads();
    if (w < 2)
        store16(slots + (60 + w) * SLOT, prod2(slots, 56 + 2 * w, 56 + 2 * w + 1, lane), lane, w & 1);
    __syncthreads();
    f32x4 root = prod2(slots, 60, 61, lane);

    if (w == 0) {
        unsigned short* cp = (unsigned short*)(wsb + WS_CP) + ((size_t)b * K + chunk) * 256;
        if (chunk & 1) {
            ull pk = (ull)f2bf(root[0]) | ((ull)f2bf(root[1]) << 16)
                   | ((ull)f2bf(root[2]) << 32) | ((ull)f2bf(root[3]) << 48);
            *(ull*)(cp + col * 16 + quad * 4) = pk;
        } else {
#pragma unroll
            for (int r = 0; r < 4; r++) cp[(quad * 4 + r) * 16 + col] = f2bf(root[r]);
        }
    }
}

__global__ void __launch_bounds__(256) reduce_kernel(unsigned char* __restrict__ wsb,
                                                     float* __restrict__ out) {
    // Same 62-slot layout as chunk: lv1 (from global) -> 0..31, then tree over 32.
    __shared__ __align__(16) unsigned short slots[62 * SLOT];
    int tid = threadIdx.x, lane = tid & 63, w = tid >> 6;
    int col = lane & 15, quad = lane >> 4;
    int b = blockIdx.x;

    const unsigned short* cpb = (const unsigned short*)(wsb + WS_CP) + (size_t)b * K * 256;
    // lv1: 32 products of global pairs (even = A row-major, odd = B [col][row]).
#pragma unroll
    for (int i2 = 0; i2 < 8; i2++) {
        int i = 8 * w + i2;
        bf16x8 a  = ldfrag_g(cpb + (size_t)(2 * i) * 256, lane);
        bf16x8 bb = ldfrag_g(cpb + (size_t)(2 * i + 1) * 256, lane);
        f32x4 c0 = {0.f, 0.f, 0.f, 0.f};
        f32x4 d = __builtin_amdgcn_mfma_f32_16x16x32_bf16(a, bb, c0, 0, 0, 0);
        store16(slots + i * SLOT, d, lane, i & 1);
    }
#pragma unroll
    for (int i2 = 0; i2 < 4; i2++) {
        int i = 4 * w + i2;
        store16(slots + (32 + i) * SLOT, prod2(slots, 2 * i, 2 * i + 1, lane), lane, i & 1);
    }
#pragma unroll
    for (int i2 = 0; i2 < 2; i2++) {
        int i = 2 * w + i2;
        store16(slots + (48 + i) * SLOT, prod2(slots, 32 + 2 * i, 32 + 2 * i + 1, lane), lane, i & 1);
    }
    store16(slots + (56 + w) * SLOT, prod2(slots, 48 + 2 * w, 48 + 2 * w + 1, lane), lane, w & 1);
    __syncthreads();
    if (w < 2)
        store16(slots + (60 + w) * SLOT, prod2(slots, 56 + 2 * w, 56 + 2 * w + 1, lane), lane, w & 1);
    __syncthreads();
    f32x4 troot = prod2(slots, 60, 61, lane);

    if (w == 0) {
        const float* initp = (const float*)(wsb + WS_INIT);
        const float* acclog = (const float*)(wsb + WS_ACC);
        float part = 0.f;
#pragma unroll
        for (int r = 0; r < 4; r++) part += initp[quad * 4 + r] * troot[r];
        part += __shfl_xor(part, 16);
        part += __shfl_xor(part, 32);
        float lp = logf(fmaxf(part, 0.f) + 1e-30f) + acclog[col];
        float mx = lp;
#pragma unroll
        for (int d = 1; d < 16; d <<= 1) mx = fmaxf(mx, __shfl_xor(mx, d));
        float a2 = isfinite(mx) ? mx : 0.0f;  // jax.nn.logsumexp semantics
        float sm = expf(lp - a2);
#pragma unroll
        for (int d = 1; d < 16; d <<= 1) sm += __shfl_xor(sm, d);
        float cl = ((const float*)(wsb + WS_CLOG))[b * K + lane];
#pragma unroll
        for (int d = 1; d < 64; d <<= 1) cl += __shfl_xor(cl, d);
        if (lane == 0) out[b] = logf(sm) + a2 + cl;
    }
}

extern "C" void kernel_launch(void* const* d_in, const int* in_sizes, int n_in,
                              void* d_out, int out_size, void* d_ws, size_t ws_size,
                              hipStream_t stream) {
    const float* logx = (const float*)d_in[0];   // (B, L, C) f32
    const float* init = (const float*)d_in[1];   // (S,) f32
    const float* T    = (const float*)d_in[2];   // (S, C, S) f32
    const float* acc  = (const float*)d_in[3];   // (S,) f32
    unsigned char* wsb = (unsigned char*)d_ws;
    float* out = (float*)d_out;

    prepall_kernel<<<64, 256, 0, stream>>>(init, T, acc, wsb);
    chunk_kernel<<<dim3(K, NB), 256, 0, stream>>>(logx, wsb);
    reduce_kernel<<<NB, 256, 0, stream>>>(wsb, out);
}

// Round 9
// 92.563 us; speedup vs baseline: 2.6537x; 1.0130x over previous
//
#include <hip/hip_runtime.h>
#include <math.h>

#define S 16
#define C 8
#define NB 64   // batch
#define L 4096
#define K 64    // chunks per batch
#define LC 64   // steps per chunk

#define SLOT 324  // bf16 elems per matrix slot = 648 B (162 banks % 32 == 2 -> quad-distinct slot bases)
#define RS 20     // row stride in elems (40 B -> conflict-free row-major scatters)

typedef __attribute__((ext_vector_type(8))) short bf16x8;
typedef __attribute__((ext_vector_type(4))) short bf16x4;
typedef __attribute__((ext_vector_type(4))) float f32x4;
typedef unsigned long long ull;

// ws byte layout:
#define WS_INIT 0       // f32[16]
#define WS_ACC  64      // f32[16]
#define WS_CLOG 512     // f32[4096] (16 KB)
#define WS_TTT  16896   // bf16 TTT[(p*16+n)][cc'=64] (32 KB), B-frag-ready
#define WS_CP   49664   // bf16 chunkP[4096][256]; even chunk row-major, odd [col][row]

__device__ __forceinline__ float hsig(float x) {
    return x / (1.0f + fabsf(x)) * 0.5f + 0.5f;
}
__device__ __forceinline__ unsigned short f2bf(float f) {
    unsigned int u = __float_as_uint(f);
    return (unsigned short)((u + 0x7fffu + ((u >> 16) & 1u)) >> 16);
}

__device__ __forceinline__ bf16x8 ldfrag(const unsigned short* base, int lane) {
    int col = lane & 15, quad = lane >> 4;
    bf16x8 f = {0, 0, 0, 0, 0, 0, 0, 0};
    if (quad < 2) {  // quads 2,3 are the K-pad (16 -> 32)
        const bf16x4* p = (const bf16x4*)(base + col * RS + quad * 8);
        bf16x4 lo = p[0], hi = p[1];
        f[0] = lo[0]; f[1] = lo[1]; f[2] = lo[2]; f[3] = lo[3];
        f[4] = hi[0]; f[5] = hi[1]; f[6] = hi[2]; f[7] = hi[3];
    }
    return f;
}

__device__ __forceinline__ f32x4 prod2(const unsigned short* slots, int sa, int sb, int lane) {
    bf16x8 a = ldfrag(slots + sa * SLOT, lane);
    bf16x8 b = ldfrag(slots + sb * SLOT, lane);
    f32x4 c = {0.f, 0.f, 0.f, 0.f};
    return __builtin_amdgcn_mfma_f32_16x16x32_bf16(a, b, c, 0, 0, 0);
}

// Frag straight from a packed global chunkP matrix (even chunk row-major ->
// A-operand; odd chunk [col][row] -> B-operand): 16 B/lane at col*16+quad*8.
__device__ __forceinline__ bf16x8 ldfrag_g(const unsigned short* base, int lane) {
    int col = lane & 15, quad = lane >> 4;
    bf16x8 f = {0, 0, 0, 0, 0, 0, 0, 0};
    if (quad < 2) f = *(const bf16x8*)(base + col * 16 + quad * 8);
    return f;
}

__device__ __forceinline__ void store16(unsigned short* slot, f32x4 d, int lane, bool odd) {
    int col = lane & 15, quad = lane >> 4;
    if (odd) {
        ull pk = (ull)f2bf(d[0]) | ((ull)f2bf(d[1]) << 16)
               | ((ull)f2bf(d[2]) << 32) | ((ull)f2bf(d[3]) << 48);
        *(ull*)(slot + col * RS + quad * 4) = pk;
    } else {
#pragma unroll
        for (int r = 0; r < 4; r++) slot[(quad * 4 + r) * RS + col] = f2bf(d[r]);
    }
}

// In-place balanced tree over 32 matrices in slots 0..31 (slot i layout parity
// i&1). Level k's product i reads slots (2^k)i (even layout) and (2^k)i+2^(k-1)
// (odd layout) and overwrites slot (2^k)i with layout parity i&1. Wave w owns
// lv1 i in [4w,4w+4), lv2 i in [2w,2w+2), lv3 i=w -> all within-wave LDS deps,
// barrier-free until lv4 (cross-wave).
__device__ __forceinline__ f32x4 tree32_inplace(unsigned short* slots, int lane, int w) {
#pragma unroll
    for (int i2 = 0; i2 < 4; i2++) {   // lv1: 16 products
        int i = 4 * w + i2;
        store16(slots + (2 * i) * SLOT, prod2(slots, 2 * i, 2 * i + 1, lane), lane, i & 1);
    }
#pragma unroll
    for (int i2 = 0; i2 < 2; i2++) {   // lv2: 8 products
        int i = 2 * w + i2;
        store16(slots + (4 * i) * SLOT, prod2(slots, 4 * i, 4 * i + 2, lane), lane, i & 1);
    }
    // lv3: 4 products, i = w
    store16(slots + (8 * w) * SLOT, prod2(slots, 8 * w, 8 * w + 4, lane), lane, w & 1);
    __syncthreads();
    if (w < 2)  // lv4: 2 products
        store16(slots + (16 * w) * SLOT, prod2(slots, 16 * w, 16 * w + 8, lane), lane, w & 1);
    __syncthreads();
    return prod2(slots, 0, 16, lane);  // root
}

// 64 blocks: every block redundantly normalizes T in LDS (cheap), then block cc
// computes TTT[.][cc] = (T_c * T_{c'}) column. Block 0 also writes init/acc.
__global__ void __launch_bounds__(256) prepall_kernel(const float* __restrict__ invh_init,
                                                      const float* __restrict__ invh_T,
                                                      const float* __restrict__ invh_acc,
                                                      unsigned char* __restrict__ wsb) {
    __shared__ float Tn[2048];  // Tn[(p*8+c)*16 + n]
    int t = threadIdx.x;  // 256
    int cc = blockIdx.x, c = cc >> 3, c2 = cc & 7;
    if (t < S * C) {
        float v[S]; float s = 0.f;
#pragma unroll
        for (int n = 0; n < S; n++) { v[n] = hsig(invh_T[t * S + n]); s += v[n]; }
        float inv = 1.f / s;
#pragma unroll
        for (int n = 0; n < S; n++) Tn[t * S + n] = v[n] * inv;
    }
    __syncthreads();
    int p = t >> 4, n = t & 15;
    float a = 0.f;
#pragma unroll
    for (int k = 0; k < S; k++) a += Tn[(p * 8 + c) * 16 + k] * Tn[(k * 8 + c2) * 16 + n];
    ((unsigned short*)(wsb + WS_TTT))[t * 64 + cc] = f2bf(a);

    if (cc == 0 && t < S) {
        float s = 0.f;
#pragma unroll
        for (int k = 0; k < S; k++) s += hsig(invh_init[k]);
        ((float*)(wsb + WS_INIT))[t] = hsig(invh_init[t]) / s;
        ((float*)(wsb + WS_ACC))[t] = logf(hsig(invh_acc[t]));
    }
}

__global__ void __launch_bounds__(256) chunk_kernel(const float* __restrict__ logx,
                                                    unsigned char* __restrict__ wsb) {
    __shared__ __align__(16) unsigned short slots[32 * SLOT];  // 20736 B
    __shared__ float xs[2 * LC * C];                           // 2048 B x-stage

    int tid = threadIdx.x, lane = tid & 63, w = tid >> 6;
    int col = lane & 15, quad = lane >> 4;
    int chunk = blockIdx.x, b = blockIdx.y;

    // B-frags for the pair-product construct (wave w owns p-tiles 4w..4w+3).
    const unsigned short* TTT = (const unsigned short*)(wsb + WS_TTT);
    bf16x8 bfr[4][2];
#pragma unroll
    for (int jj = 0; jj < 4; jj++) {
        int t = 4 * w + jj;
#pragma unroll
        for (int kk = 0; kk < 2; kk++)
            bfr[jj][kk] = *(const bf16x8*)(TTT + (t * 16 + col) * 64 + kk * 32 + quad * 8);
    }

    // Stage logx tile (512 f32, coalesced).
    const float* xg = logx + ((size_t)b * L + (size_t)chunk * LC) * C;
    xs[tid] = xg[tid];
    xs[tid + 256] = xg[tid + 256];
    __syncthreads();

    // Per-step logsumexp normalize (wave 0); chunkLog written here.
    if (tid < LC) {
        float v[C]; float m = -INFINITY;
#pragma unroll
        for (int c = 0; c < C; c++) { v[c] = xs[tid * C + c]; m = fmaxf(m, v[c]); }
        float s = 0.f;
#pragma unroll
        for (int c = 0; c < C; c++) { v[c] = __expf(v[c] - m); s += v[c]; }
        float lx = m + __logf(s);
        float inv = 1.0f / s;
#pragma unroll
        for (int c = 0; c < C; c++) xs[tid * C + c] = v[c] * inv;
        float cl = lx;
#pragma unroll
        for (int d = 1; d < 64; d <<= 1) cl += __shfl_xor(cl, d);
        if (lane == 0) ((float*)(wsb + WS_CLOG))[b * K + chunk] = cl;
    }
    __syncthreads();

    // A-frags: y[i][cc'] = xn[2i][c]*xn[2i+1][c'].
    bf16x8 afr[2][2];
#pragma unroll
    for (int mt = 0; mt < 2; mt++) {
        int i2 = 2 * (mt * 16 + col);
        const float4* x1p = (const float4*)(xs + (i2 + 1) * 8);
        float4 xa = x1p[0], xb = x1p[1];
#pragma unroll
        for (int kk = 0; kk < 2; kk++) {
            float x0 = xs[i2 * 8 + kk * 4 + quad];
            bf16x8 a;
            a[0] = (short)f2bf(x0 * xa.x); a[1] = (short)f2bf(x0 * xa.y);
            a[2] = (short)f2bf(x0 * xa.z); a[3] = (short)f2bf(x0 * xa.w);
            a[4] = (short)f2bf(x0 * xb.x); a[5] = (short)f2bf(x0 * xb.y);
            a[6] = (short)f2bf(x0 * xb.z); a[7] = (short)f2bf(x0 * xb.w);
            afr[mt][kk] = a;
        }
    }

    // Pair-product construct -> slots 0..31 (parity i&1).
#pragma unroll
    for (int mt = 0; mt < 2; mt++)
#pragma unroll
        for (int jj = 0; jj < 4; jj++) {
            f32x4 acc = {0.f, 0.f, 0.f, 0.f};
#pragma unroll
            for (int kk = 0; kk < 2; kk++)
                acc = __builtin_amdgcn_mfma_f32_16x16x32_bf16(afr[mt][kk], bfr[jj][kk], acc, 0, 0, 0);
            int t = 4 * w + jj;  // = p
#pragma unroll
            for (int r = 0; r < 4; r++) {
                int i = mt * 16 + quad * 4 + r;
                int off = (i & 1) ? (col * RS + t) : (t * RS + col);
                slots[i * SLOT + off] = f2bf(acc[r]);
            }
        }
    __syncthreads();

    f32x4 root = tree32_inplace(slots, lane, w);

    if (w == 0) {
        unsigned short* cp = (unsigned short*)(wsb + WS_CP) + ((size_t)b * K + chunk) * 256;
        if (chunk & 1) {
            ull pk = (ull)f2bf(root[0]) | ((ull)f2bf(root[1]) << 16)
                   | ((ull)f2bf(root[2]) << 32) | ((ull)f2bf(root[3]) << 48);
            *(ull*)(cp + col * 16 + quad * 4) = pk;
        } else {
#pragma unroll
            for (int r = 0; r < 4; r++) cp[(quad * 4 + r) * 16 + col] = f2bf(root[r]);
        }
    }
}

__global__ void __launch_bounds__(256) reduce_kernel(unsigned char* __restrict__ wsb,
                                                     float* __restrict__ out) {
    __shared__ __align__(16) unsigned short slots[32 * SLOT];  // 20736 B
    int tid = threadIdx.x, lane = tid & 63, w = tid >> 6;
    int col = lane & 15, quad = lane >> 4;
    int b = blockIdx.x;

    const unsigned short* cpb = (const unsigned short*)(wsb + WS_CP) + (size_t)b * K * 256;
    // lv0: 32 products of global pairs (even = A row-major, odd = B [col][row]);
    // wave w writes slots 8w..8w+7, which only wave w reads in the tree's lv1.
#pragma unroll
    for (int i2 = 0; i2 < 8; i2++) {
        int i = 8 * w + i2;
        bf16x8 a  = ldfrag_g(cpb + (size_t)(2 * i) * 256, lane);
        bf16x8 bb = ldfrag_g(cpb + (size_t)(2 * i + 1) * 256, lane);
        f32x4 c0 = {0.f, 0.f, 0.f, 0.f};
        f32x4 d = __builtin_amdgcn_mfma_f32_16x16x32_bf16(a, bb, c0, 0, 0, 0);
        store16(slots + i * SLOT, d, lane, i & 1);
    }

    f32x4 troot = tree32_inplace(slots, lane, w);

    if (w == 0) {
        const float* initp = (const float*)(wsb + WS_INIT);
        const float* acclog = (const float*)(wsb + WS_ACC);
        float part = 0.f;
#pragma unroll
        for (int r = 0; r < 4; r++) part += initp[quad * 4 + r] * troot[r];
        part += __shfl_xor(part, 16);
        part += __shfl_xor(part, 32);
        float lp = logf(fmaxf(part, 0.f) + 1e-30f) + acclog[col];
        float mx = lp;
#pragma unroll
        for (int d = 1; d < 16; d <<= 1) mx = fmaxf(mx, __shfl_xor(mx, d));
        float a2 = isfinite(mx) ? mx : 0.0f;  // jax.nn.logsumexp semantics
        float sm = expf(lp - a2);
#pragma unroll
        for (int d = 1; d < 16; d <<= 1) sm += __shfl_xor(sm, d);
        float cl = ((const float*)(wsb + WS_CLOG))[b * K + lane];
#pragma unroll
        for (int d = 1; d < 64; d <<= 1) cl += __shfl_xor(cl, d);
        if (lane == 0) out[b] = logf(sm) + a2 + cl;
    }
}

extern "C" void kernel_launch(void* const* d_in, const int* in_sizes, int n_in,
                              void* d_out, int out_size, void* d_ws, size_t ws_size,
                              hipStream_t stream) {
    const float* logx = (const float*)d_in[0];   // (B, L, C) f32
    const float* init = (const float*)d_in[1];   // (S,) f32
    const float* T    = (const float*)d_in[2];   // (S, C, S) f32
    const float* acc  = (const float*)d_in[3];   // (S,) f32
    unsigned char* wsb = (unsigned char*)d_ws;
    float* out = (float*)d_out;

    prepall_kernel<<<64, 256, 0, stream>>>(init, T, acc, wsb);
    chunk_kernel<<<dim3(K, NB), 256, 0, stream>>>(logx, wsb);
    reduce_kernel<<<NB, 256, 0, stream>>>(wsb, out);
}